// Round 24
// baseline (147.668 us; speedup 1.0000x reference)
//
#include <hip/hip_runtime.h>
#include <hip/hip_bf16.h>

// Problem constants
#define Nn   32
#define Ee   512
#define DIN  300
#define DOUT 300
#define NT   4
#define QD   300
#define SLOPE 0.2f
#define ROWS 64   // rows per attn block (1 block/CU, fat tile)
#define CPAD 320  // padded d-dim for hmT (col-tiles 0..18 used; 19 is dead)
#define SSTR 516  // S[r][j] stride (mult of 4 for b128; rotates banks)
#define USTR 65   // coefU[j][r] stride
#define XROWS 16384

typedef __attribute__((ext_vector_type(8))) short bf16x8;
typedef __attribute__((ext_vector_type(4))) float f32x4;
typedef __attribute__((ext_vector_type(4))) unsigned short u16x4;

__device__ inline unsigned short f2bf(float x) {
    __hip_bfloat16 h = __float2bfloat16(x);   // RNE
    return *reinterpret_cast<unsigned short*>(&h);
}
__device__ inline float bf2f(unsigned short u) {
    __hip_bfloat16 h = *reinterpret_cast<__hip_bfloat16*>(&u);
    return __bfloat162float(h);
}
// sdl bank swizzle: moves j[6:5] into bank bits [1:0]; bijective.
__device__ inline int swzj(int j) { return j ^ ((j >> 5) & 3); }

// ---------------------------------------------------------------------------
// K0: prep. W3T split planes; zero UT/GT planes; X -> padded bf16 split
// planes Xhi/Xlo[16384][320] (k>=300 zero) so hm's A-frags are pure 16B loads.
__global__ __launch_bounds__(256) void prep_kernel(
    const float* __restrict__ W3,          // (300, 300)  row k, col d
    const float* __restrict__ Xsrc,        // (16384, 300)
    unsigned short* __restrict__ W3T_hi,   // (320, 320)
    unsigned short* __restrict__ W3T_lo,
    unsigned short* __restrict__ UTh,      // (32, 16, 320)
    unsigned short* __restrict__ UTl,
    unsigned short* __restrict__ GTh,      // (4, 64, 320)
    unsigned short* __restrict__ GTl,
    unsigned short* __restrict__ Xhi,      // (16384, 320)
    unsigned short* __restrict__ Xlo)
{
    int idx = blockIdx.x * 256 + threadIdx.x;   // grid 640 -> 163840 threads
    if (idx < 320 * 320) {
        int c = idx / 320, k = idx - c * 320;
        float v = (c < DOUT && k < DIN) ? W3[(size_t)k * DOUT + c] : 0.f;
        unsigned short h = f2bf(v);
        W3T_hi[idx] = h;
        W3T_lo[idx] = f2bf(v - bf2f(h));
    }
    if (idx < 32 * 16 * 320) { UTh[idx] = 0; UTl[idx] = 0; }
    if (idx < 4 * 64 * 320)  { GTh[idx] = 0; GTl[idx] = 0; }

    // X split: grid-stride over 16384*320
    for (size_t e = idx; e < (size_t)XROWS * 320; e += 163840) {
        int row = (int)(e / 320);
        int k   = (int)(e - (size_t)row * 320);
        float v = (k < DIN) ? Xsrc[(size_t)row * DIN + k] : 0.f;
        unsigned short h = f2bf(v);
        Xhi[e] = h;
        Xlo[e] = f2bf(v - bf2f(h));
    }
}

// ---------------------------------------------------------------------------
// K1a: gates1 partial. grid (75, NT, 4), block 256.
__global__ __launch_bounds__(256) void gates1_part_kernel(
    const float* __restrict__ q,    // (32, 300)
    const float* __restrict__ W1,   // (4, 300, 600)
    float* __restrict__ t1p)        // (4, 4, 32, 600)
{
    int i = blockIdx.y, z = blockIdx.z;
    int idx = blockIdx.x * 256 + threadIdx.x;
    int n = idx / 600, j = idx - n * 600;
    const float* W1i = W1 + (size_t)i * QD * 600;
    const float* qn = q + n * QD;
    int k0 = z * 75;
    float a0 = 0.f;
    #pragma unroll 5
    for (int k = k0; k < k0 + 75; ++k)
        a0 += qn[k] * W1i[(size_t)k * 600 + j];
    t1p[((size_t)(z * NT + i) * Nn + n) * 600 + j] = a0;
}

// K1a-fin: t1 = relu(sum_z t1p). grid (75, NT).
__global__ __launch_bounds__(256) void gates1_fin_kernel(
    const float* __restrict__ t1p, float* __restrict__ t1)
{
    int i = blockIdx.y;
    int idx = blockIdx.x * 256 + threadIdx.x;
    size_t o = ((size_t)i * Nn) * 600 + idx;
    float s = t1p[o] + t1p[o + 76800] + t1p[o + 2 * 76800] + t1p[o + 3 * 76800];
    t1[o] = fmaxf(s, 0.f);
}

// ---------------------------------------------------------------------------
// K1b: gates2 partial. K=600, 4 slabs of 150.
__global__ __launch_bounds__(256) void gates2_part_kernel(
    const float* __restrict__ t1,   // (4, 32, 600)
    const float* __restrict__ W2,   // (4, 600, 600)
    float* __restrict__ gp)         // (4, 4, 32, 600)
{
    int i = blockIdx.y, z = blockIdx.z;
    int idx = blockIdx.x * 256 + threadIdx.x;
    int n = idx / 600, j = idx - n * 600;
    const float* W2i = W2 + (size_t)i * 600 * 600;
    const float* tn = t1 + ((size_t)i * Nn + n) * 600;
    int k0 = z * 150;
    float a0 = 0.f, a1 = 0.f;
    #pragma unroll 5
    for (int k = k0; k < k0 + 150; k += 2) {
        a0 += tn[k]     * W2i[(size_t)k * 600 + j];
        a1 += tn[k + 1] * W2i[(size_t)(k + 1) * 600 + j];
    }
    gp[((size_t)(z * NT + i) * Nn + n) * 600 + j] = a0 + a1;
}

// K1b-fin: gate = sigmoid(sum_z gp) * a  -> GT split planes [i][2n+s][d].
__global__ __launch_bounds__(256) void gates2_fin_kernel(
    const float* __restrict__ gp,
    const float* __restrict__ a,    // (4, 600)
    unsigned short* __restrict__ GTh,   // (4, 64, 320)
    unsigned short* __restrict__ GTl)
{
    int i = blockIdx.y;
    int idx = blockIdx.x * 256 + threadIdx.x;
    int n = idx / 600, j = idx - n * 600;
    size_t o = ((size_t)i * Nn + n) * 600 + j;
    float s = gp[o] + gp[o + 76800] + gp[o + 2 * 76800] + gp[o + 3 * 76800];
    float w = (1.f / (1.f + __expf(-s))) * a[(size_t)i * 600 + j];
    int s2 = (j >= DOUT) ? 1 : 0;
    int d = j - s2 * DOUT;
    int c = 2 * n + s2;
    size_t go = ((size_t)i * 64 + c) * 320 + d;
    unsigned short h = f2bf(w);
    GTh[go] = h;
    GTl[go] = f2bf(w - bf2f(h));
}

// ---------------------------------------------------------------------------
// K2: uvec via MFMA. grid (5, NT), block 256 (4 waves).
__global__ __launch_bounds__(256) void uvec_mfma_kernel(
    const float* __restrict__ W,            // (4, 300, 300)
    const unsigned short* __restrict__ GTh, // (4, 64, 320)
    const unsigned short* __restrict__ GTl,
    unsigned short* __restrict__ UTh,       // (32, 16, 320)
    unsigned short* __restrict__ UTl)
{
    int mc = blockIdx.x, i = blockIdx.y;
    int tid = threadIdx.x, wv = tid >> 6, lane = tid & 63;
    int g = lane >> 4, cr = lane & 15;
    int m0 = mc * 64 + wv * 16;
    int arow = m0 + cr;
    const float* wr = W + (size_t)i * DIN * DOUT
                        + (size_t)(arow < DIN ? arow : 0) * DOUT;

    f32x4 acc[4];
    #pragma unroll
    for (int nt = 0; nt < 4; ++nt) acc[nt] = (f32x4){0.f, 0.f, 0.f, 0.f};

    for (int ks = 0; ks < 10; ++ks) {
        int k0 = ks * 32 + 8 * g;
        float x8[8];
        if (ks < 9) {
            f32x4 v0 = *(const f32x4*)(wr + k0);
            f32x4 v1 = *(const f32x4*)(wr + k0 + 4);
            #pragma unroll
            for (int j = 0; j < 4; ++j) { x8[j] = v0[j]; x8[4 + j] = v1[j]; }
        } else {
            #pragma unroll
            for (int j = 0; j < 8; ++j) {
                int d = k0 + j;
                x8[j] = (d < DOUT) ? wr[d] : 0.f;
            }
        }
        bf16x8 ahi, alo;
        #pragma unroll
        for (int j = 0; j < 8; ++j) {
            unsigned short h = f2bf(x8[j]);
            ahi[j] = (short)h;
            alo[j] = (short)f2bf(x8[j] - bf2f(h));
        }
        #pragma unroll
        for (int nt = 0; nt < 4; ++nt) {
            size_t bo = ((size_t)i * 64 + nt * 16 + cr) * 320 + k0;
            bf16x8 bh = *(const bf16x8*)(GTh + bo);
            bf16x8 bl = *(const bf16x8*)(GTl + bo);
            acc[nt] = __builtin_amdgcn_mfma_f32_16x16x32_bf16(ahi, bh, acc[nt], 0, 0, 0);
            acc[nt] = __builtin_amdgcn_mfma_f32_16x16x32_bf16(ahi, bl, acc[nt], 0, 0, 0);
            acc[nt] = __builtin_amdgcn_mfma_f32_16x16x32_bf16(alo, bh, acc[nt], 0, 0, 0);
        }
    }

    int krow = m0 + 4 * g;
    if (krow < DIN) {
        #pragma unroll
        for (int nt = 0; nt < 4; ++nt) {
            int c = nt * 16 + cr;
            int n = c >> 1, s = c & 1;
            size_t base = ((size_t)n * 16 + 2 * i + s) * 320 + krow;
            u16x4 h4, l4;
            #pragma unroll
            for (int q = 0; q < 4; ++q) {
                float v = acc[nt][q];
                unsigned short h = f2bf(v);
                h4[q] = h;
                l4[q] = f2bf(v - bf2f(h));
            }
            *(u16x4*)(UTh + base) = h4;
            *(u16x4*)(UTl + base) = l4;
        }
    }
}

// ---------------------------------------------------------------------------
// K4: MFMA hm GEMM + fused sdot. 64-row fat tile, NOW 1024 threads (16
// waves): A-frags are direct 16B loads from pre-split Xhi/Xlo (padded 320/row)
// -> the round-22 per-wave A-build duplication cost is gone; extra waves are
// pure latency-hiding. Wave wv owns col-tiles {wv, wv+16} ∩ [0,19).
__global__ __launch_bounds__(1024) void hm_mfma_kernel(
    const unsigned short* __restrict__ Xhi,    // (16384, 320)
    const unsigned short* __restrict__ Xlo,
    const float* __restrict__ mask,            // (16384)
    const unsigned short* __restrict__ W3T_hi, // (320, 320)
    const unsigned short* __restrict__ W3T_lo,
    const unsigned short* __restrict__ UTh,    // (32, 16, 320)
    const unsigned short* __restrict__ UTl,
    unsigned short* __restrict__ hmT_hi,       // (32, CPAD, 512)
    unsigned short* __restrict__ hmT_lo,
    float* __restrict__ ssrc,                  // (4, 32, 512)
    float* __restrict__ sdst)
{
    int tid = threadIdx.x, wv = tid >> 6, lane = tid & 63;
    int g = lane >> 4, cr = lane & 15;
    int f  = blockIdx.x;                      // 0..255
    int n  = (f & 7) * 4 + ((f >> 3) & 3);    // XCD-local n (matches attn64)
    int j0 = (f >> 5) * 64;                   // 0..448
    size_t row0 = (size_t)n * Ee + j0;

    __shared__ float maskL[64];
    if (tid < 64) maskL[tid] = mask[row0 + tid];
    __syncthreads();

    f32x4 acc[2][4];
    f32x4 sacc[4];
    #pragma unroll
    for (int t = 0; t < 2; ++t)
        #pragma unroll
        for (int m = 0; m < 4; ++m) acc[t][m] = (f32x4){0.f, 0.f, 0.f, 0.f};
    #pragma unroll
    for (int m = 0; m < 4; ++m) sacc[m] = (f32x4){0.f, 0.f, 0.f, 0.f};

    for (int ks = 0; ks < 10; ++ks) {
        int k0 = ks * 32 + 8 * g;     // per-lane k base
        bf16x8 ahi[4], alo[4];
        #pragma unroll
        for (int m = 0; m < 4; ++m) {
            size_t ao = (row0 + m * 16 + cr) * 320 + k0;
            ahi[m] = *(const bf16x8*)(Xhi + ao);
            alo[m] = *(const bf16x8*)(Xlo + ao);
        }
        #pragma unroll
        for (int t = 0; t < 2; ++t) {
            int ct = wv + 16 * t;
            if (ct < 19) {
                int c = ct * 16 + cr;
                bf16x8 bh = *(const bf16x8*)(W3T_hi + (size_t)c * 320 + k0);
                bf16x8 bl = *(const bf16x8*)(W3T_lo + (size_t)c * 320 + k0);
                #pragma unroll
                for (int m = 0; m < 4; ++m) {
                    acc[t][m] = __builtin_amdgcn_mfma_f32_16x16x32_bf16(ahi[m], bh, acc[t][m], 0, 0, 0);
                    acc[t][m] = __builtin_amdgcn_mfma_f32_16x16x32_bf16(ahi[m], bl, acc[t][m], 0, 0, 0);
                    acc[t][m] = __builtin_amdgcn_mfma_f32_16x16x32_bf16(alo[m], bh, acc[t][m], 0, 0, 0);
                }
            }
        }
        if (wv == 0) {
            bf16x8 uh = *(const bf16x8*)(UTh + ((size_t)n * 16 + cr) * 320 + k0);
            bf16x8 ul = *(const bf16x8*)(UTl + ((size_t)n * 16 + cr) * 320 + k0);
            #pragma unroll
            for (int m = 0; m < 4; ++m) {
                sacc[m] = __builtin_amdgcn_mfma_f32_16x16x32_bf16(ahi[m], uh, sacc[m], 0, 0, 0);
                sacc[m] = __builtin_amdgcn_mfma_f32_16x16x32_bf16(ahi[m], ul, sacc[m], 0, 0, 0);
                sacc[m] = __builtin_amdgcn_mfma_f32_16x16x32_bf16(alo[m], uh, sacc[m], 0, 0, 0);
            }
        }
    }

    // hm epilogue: mask, split, transposed store (q contiguous in j -> 8B)
    #pragma unroll
    for (int t = 0; t < 2; ++t) {
        int ct = wv + 16 * t;
        if (ct < 19) {
            int c = ct * 16 + cr;
            #pragma unroll
            for (int m = 0; m < 4; ++m) {
                u16x4 h4, l4;
                #pragma unroll
                for (int qq = 0; qq < 4; ++qq) {
                    float v = acc[t][m][qq] * maskL[m * 16 + 4 * g + qq];
                    unsigned short h = f2bf(v);
                    h4[qq] = h;
                    l4[qq] = f2bf(v - bf2f(h));
                }
                size_t off = ((size_t)(n * CPAD + c)) * Ee + j0 + m * 16 + 4 * g;
                *(u16x4*)(hmT_hi + off) = h4;
                *(u16x4*)(hmT_lo + off) = l4;
            }
        }
    }

    // sdot epilogue: D[row=m*16+4g+q][c=cr], c=2i -> ssrc, c=2i+1 -> sdst
    if (wv == 0 && cr < 8) {
        int i = cr >> 1;
        float* dst = (cr & 1) ? sdst : ssrc;
        #pragma unroll
        for (int m = 0; m < 4; ++m)
            #pragma unroll
            for (int qq = 0; qq < 4; ++qq)
                dst[((size_t)i * Nn + n) * Ee + j0 + m * 16 + 4 * g + qq] = sacc[m][qq];
    }
}

// ---------------------------------------------------------------------------
// K5: FUSED attn, 64-row fat tile, 1024 threads (round-21 form, KEPT).
__global__ __launch_bounds__(1024, 1) void attn64_kernel(
    const int*   __restrict__ adj,      // (N, E, E)
    const float* __restrict__ ssrc,     // (4, N, E)
    const float* __restrict__ sdst,     // (4, N, E)
    const unsigned short* __restrict__ hmT_hi,  // (32, CPAD, 512)
    const unsigned short* __restrict__ hmT_lo,
    float* __restrict__ out)            // (N, E, 300)
{
    int f  = blockIdx.x;                     // 0..255
    int n  = (f & 7) * 4 + ((f >> 3) & 3);   // XCD-local n
    int rt = f >> 5;                         // 0..7
    int tid = threadIdx.x;
    int row0 = rt * ROWS;

    __shared__ unsigned uni[Ee * USTR];   // 33280 dwords = 133.1 KB (union)
    __shared__ float sdl[NT * Ee];        // 8 KB, XOR-swizzled
    __shared__ float ssl[NT * 65];        // padded
    float* S = (float*)uni;               // phase A view: S[r*SSTR + j]

    for (int idx = tid; idx < NT * Ee; idx += 1024) {
        int i = idx >> 9, j = idx & (Ee - 1);
        sdl[i * Ee + swzj(j)] = sdst[((size_t)i * Nn + n) * Ee + j];
    }
    if (tid < NT * ROWS) {
        int i = tid >> 6, r = tid & 63;
        ssl[i * 65 + r] = ssrc[((size_t)i * Nn + n) * Ee + row0 + r];
    }
    __syncthreads();

    // scores: int4 adj, swizzled sdl gather, aligned f4 writes
    const int* adjb = adj + ((size_t)n * Ee + row0) * Ee;
    for (int idx4 = tid; idx4 < (ROWS * Ee) / 4; idx4 += 1024) {
        int r  = idx4 >> 7;
        int jb = (idx4 & 127) << 2;
        int xw = (jb >> 5) & 3;
        int4 t4 = *(const int4*)(adjb + (idx4 << 2));
        int tv[4] = {t4.x, t4.y, t4.z, t4.w};
        f32x4 v4;
        #pragma unroll
        for (int u = 0; u < 4; ++u) {
            int t = tv[u];
            float v;
            if (t > 0) {
                float x = ssl[(t - 1) * 65 + r] + sdl[(t - 1) * Ee + jb + (u ^ xw)];
                v = (x >= 0.f) ? x : SLOPE * x;
            } else {
                v = -1e30f;
            }
            v4[u] = v;   // column-ordered placement
        }
        *(f32x4*)(S + r * SSTR + jb) = v4;
    }
    __syncthreads();

    // softmax: wave wv owns rows wv*4..+3, values in registers
    int wv = tid >> 6, lane = tid & 63;
    float vals[4][8];
    float inv[4];
    #pragma unroll
    for (int rr = 0; rr < 4; ++rr) {
        int r = wv * 4 + rr;
        float m = -3.0e38f;
        #pragma unroll
        for (int k = 0; k < 8; ++k) {
            vals[rr][k] = S[r * SSTR + lane + 64 * k];
            m = fmaxf(m, vals[rr][k]);
        }
        #pragma unroll
        for (int off = 32; off; off >>= 1) m = fmaxf(m, __shfl_xor(m, off));
        float s = 0.f;
        #pragma unroll
        for (int k = 0; k < 8; ++k) {
            vals[rr][k] = __expf(vals[rr][k] - m);
            s += vals[rr][k];
        }
        #pragma unroll
        for (int off = 32; off; off >>= 1) s += __shfl_xor(s, off);
        inv[rr] = 1.f / s;
    }
    __syncthreads();   // all S reads done; safe to overwrite union as coefU

    // packed write coefU[j][r] (stride 65): bank = lane + const -> free
    #pragma unroll
    for (int rr = 0; rr < 4; ++rr) {
        int r = wv * 4 + rr;
        #pragma unroll
        for (int k = 0; k < 8; ++k) {
            float v = vals[rr][k] * inv[rr];
            unsigned short hi = f2bf(v);
            unsigned short lo = f2bf(v - bf2f(hi));
            uni[(lane + 64 * k) * USTR + r] = ((unsigned)hi << 16) | (unsigned)lo;
        }
    }
    __syncthreads();

    // PV: wave wv owns col-tiles {wv, wv+16} ∩ [0,19); 4 m-frags each
    int g = lane >> 4, cr = lane & 15;
    f32x4 acc[2][4];
    #pragma unroll
    for (int t = 0; t < 2; ++t)
        #pragma unroll
        for (int m = 0; m < 4; ++m) acc[t][m] = (f32x4){0.f, 0.f, 0.f, 0.f};

#define LOADB(BH, BL, KS) do {                                              \
    int kk_ = (KS) * 32 + 8 * g;                                            \
    _Pragma("unroll")                                                       \
    for (int t_ = 0; t_ < 2; ++t_) {                                        \
        int ct_ = wv + 16 * t_;                                             \
        if (ct_ < 19) {                                                     \
            size_t off_ = ((size_t)(n * CPAD + ct_ * 16 + cr)) * Ee + kk_;  \
            BH[t_] = *(const bf16x8*)(hmT_hi + off_);                       \
            BL[t_] = *(const bf16x8*)(hmT_lo + off_);                       \
        }                                                                   \
    }                                                                       \
} while (0)

#define PVSTEP(KS, BH, BL) do {                                             \
    int kk_ = (KS) * 32;                                                    \
    bf16x8 ahi_[4], alo_[4];                                                \
    _Pragma("unroll")                                                       \
    for (int m_ = 0; m_ < 4; ++m_) {                                        \
        _Pragma("unroll")                                                   \
        for (int j_ = 0; j_ < 8; ++j_) {                                    \
            unsigned v_ = uni[(kk_ + 8 * g + j_) * USTR + m_ * 16 + cr];    \
            ahi_[m_][j_] = (short)(v_ >> 16);                               \
            alo_[m_][j_] = (short)(v_ & 0xffffu);                           \
        }                                                                   \
    }                                                                       \
    __builtin_amdgcn_s_setprio(1);                                          \
    _Pragma("unroll")                                                       \
    for (int t_ = 0; t_ < 2; ++t_) {                                        \
        if (wv + 16 * t_ < 19) {                                            \
            _Pragma("unroll")                                               \
            for (int m_ = 0; m_ < 4; ++m_) {                                \
                acc[t_][m_] = __builtin_amdgcn_mfma_f32_16x16x32_bf16(ahi_[m_], BH[t_], acc[t_][m_], 0, 0, 0); \
                acc[t_][m_] = __builtin_amdgcn_mfma_f32_16x16x32_bf16(ahi_[m_], BL[t_], acc[t_][m_], 0, 0, 0); \
                acc[t_][m_] = __builtin_amdgcn_mfma_f32_16x16x32_bf16(alo_[m_], BH[t_], acc[t_][m_], 0, 0, 0); \
            }                                                               \
        }                                                                   \
    }                                                                       \
    __builtin_amdgcn_s_setprio(0);                                          \
} while (0)

    bf16x8 bhA[2], blA[2], bhB[2], blB[2];
    LOADB(bhA, blA, 0);
    #pragma unroll
    for (int ks = 0; ks < 16; ks += 2) {
        LOADB(bhB, blB, ks + 1);
        PVSTEP(ks, bhA, blA);
        if (ks + 2 < 16) LOADB(bhA, blA, ks + 2);
        PVSTEP(ks + 1, bhB, blB);
    }
#undef LOADB
#undef PVSTEP

    #pragma unroll
    for (int t = 0; t < 2; ++t) {
        int ct = wv + 16 * t;
        if (ct < 19) {
            int c = ct * 16 + cr;
            if (c < DOUT) {
                #pragma unroll
                for (int m = 0; m < 4; ++m) {
                    #pragma unroll
                    for (int q = 0; q < 4; ++q) {
                        int erow = row0 + m * 16 + 4 * g + q;
                        out[((size_t)n * Ee + erow) * DOUT + c] = acc[t][m][q];
                    }
                }
            }
        }
    }
}

// ---------------------------------------------------------------------------
extern "C" void kernel_launch(void* const* d_in, const int* in_sizes, int n_in,
                              void* d_out, int out_size, void* d_ws, size_t ws_size,
                              hipStream_t stream) {
    const float* input_state = (const float*)d_in[0];
    const int*   adj         = (const int*)  d_in[1];
    const float* node_mask   = (const float*)d_in[2];
    const float* query_vec   = (const float*)d_in[3];
    const float* W_type      = (const float*)d_in[4];
    const float* a_type      = (const float*)d_in[5];
    const float* qattn_W1    = (const float*)d_in[6];
    const float* qattn_W2    = (const float*)d_in[7];
    float* out = (float*)d_out;

    // workspace layout (~47 MB)
    float* ws   = (float*)d_ws;
    float* t1   = ws;                 // 76800 f
    float* ssrc = t1   + 76800;       // 65536 f
    float* sdst = ssrc + 65536;       // 65536 f
    unsigned short* W3T_hi = (unsigned short*)(sdst + 65536);   // 102400 u16
    unsigned short* W3T_lo = W3T_hi + 320 * 320;                // 102400 u16
    unsigned short* GTh    = W3T_lo + 320 * 320;                // 81920 u16
    unsigned short* GTl    = GTh + 4 * 64 * 320;                // 81920 u16
    unsigned short* UTh    = GTl + 4 * 64 * 320;                // 163840 u16
    unsigned short* UTl    = UTh + 32 * 16 * 320;               // 163840 u16
    unsigned short* hmT_hi = UTl + 32 * 16 * 320;               // 5242880 u16
    unsigned short* hmT_lo = hmT_hi + (size_t)Nn * CPAD * Ee;   // 5242880 u16
    unsigned short* Xhi    = hmT_lo + (size_t)Nn * CPAD * Ee;   // 5242880 u16
    unsigned short* Xlo    = Xhi + (size_t)XROWS * 320;         // 5242880 u16
    float* t1p = (float*)(Xlo + (size_t)XROWS * 320);           // 307200 f
    float* gp  = t1p + 307200;                                  // 307200 f

    hipLaunchKernelGGL(prep_kernel, dim3(640), dim3(256), 0, stream,
                       W_type + 3 * DIN * DOUT, input_state,
                       W3T_hi, W3T_lo, UTh, UTl, GTh, GTl, Xhi, Xlo);
    hipLaunchKernelGGL(gates1_part_kernel, dim3(75, NT, 4), dim3(256), 0, stream,
                       query_vec, qattn_W1, t1p);
    hipLaunchKernelGGL(gates1_fin_kernel, dim3(75, NT), dim3(256), 0, stream,
                       t1p, t1);
    hipLaunchKernelGGL(gates2_part_kernel, dim3(75, NT, 4), dim3(256), 0, stream,
                       t1, qattn_W2, gp);
    hipLaunchKernelGGL(gates2_fin_kernel, dim3(75, NT), dim3(256), 0, stream,
                       gp, a_type, GTh, GTl);
    hipLaunchKernelGGL(uvec_mfma_kernel, dim3(5, NT), dim3(256), 0, stream,
                       W_type, GTh, GTl, UTh, UTl);
    hipLaunchKernelGGL(hm_mfma_kernel, dim3((Nn * Ee) / 64), dim3(1024), 0, stream,
                       Xhi, Xlo, node_mask, W3T_hi, W3T_lo, UTh, UTl,
                       hmT_hi, hmT_lo, ssrc, sdst);
    hipLaunchKernelGGL(attn64_kernel, dim3(256), dim3(1024), 0, stream,
                       adj, ssrc, sdst, hmT_hi, hmT_lo, out);
}

// Round 25
// 114.065 us; speedup vs baseline: 1.2946x; 1.2946x over previous
//
#include <hip/hip_runtime.h>
#include <hip/hip_bf16.h>

// Problem constants
#define Nn   32
#define Ee   512
#define DIN  300
#define DOUT 300
#define NT   4
#define QD   300
#define SLOPE 0.2f
#define ROWS 64   // rows per attn block (1 block/CU, fat tile)
#define CPAD 320  // padded d-dim for hmT (col-tiles 0..18 used; 19 is dead)
#define SSTR 516  // S[r][j] stride (mult of 4 for b128; rotates banks)
#define USTR 65   // coefU[j][r] stride

typedef __attribute__((ext_vector_type(8))) short bf16x8;
typedef __attribute__((ext_vector_type(4))) float f32x4;
typedef __attribute__((ext_vector_type(4))) unsigned short u16x4;

__device__ inline unsigned short f2bf(float x) {
    __hip_bfloat16 h = __float2bfloat16(x);   // RNE
    return *reinterpret_cast<unsigned short*>(&h);
}
__device__ inline float bf2f(unsigned short u) {
    __hip_bfloat16 h = *reinterpret_cast<__hip_bfloat16*>(&u);
    return __bfloat162float(h);
}
// sdl bank swizzle: moves j[6:5] into bank bits [1:0]; bijective.
__device__ inline int swzj(int j) { return j ^ ((j >> 5) & 3); }

// ---------------------------------------------------------------------------
// K0: prep. W3T split planes; zero UT planes; zero GT planes.
__global__ __launch_bounds__(256) void prep_kernel(
    const float* __restrict__ W3,          // (300, 300)  row k, col d
    unsigned short* __restrict__ W3T_hi,   // (320, 320)
    unsigned short* __restrict__ W3T_lo,
    unsigned short* __restrict__ UTh,      // (32, 16, 320)
    unsigned short* __restrict__ UTl,
    unsigned short* __restrict__ GTh,      // (4, 64, 320)
    unsigned short* __restrict__ GTl)
{
    int idx = blockIdx.x * 256 + threadIdx.x;   // grid 640
    if (idx < 320 * 320) {
        int c = idx / 320, k = idx - c * 320;
        float v = (c < DOUT && k < DIN) ? W3[(size_t)k * DOUT + c] : 0.f;
        unsigned short h = f2bf(v);
        W3T_hi[idx] = h;
        W3T_lo[idx] = f2bf(v - bf2f(h));
    }
    if (idx < 32 * 16 * 320) { UTh[idx] = 0; UTl[idx] = 0; }
    if (idx < 4 * 64 * 320)  { GTh[idx] = 0; GTl[idx] = 0; }
}

// ---------------------------------------------------------------------------
// K1a: gates1 partial. grid (75, NT, 4), block 256.
__global__ __launch_bounds__(256) void gates1_part_kernel(
    const float* __restrict__ q,    // (32, 300)
    const float* __restrict__ W1,   // (4, 300, 600)
    float* __restrict__ t1p)        // (4, 4, 32, 600)
{
    int i = blockIdx.y, z = blockIdx.z;
    int idx = blockIdx.x * 256 + threadIdx.x;
    int n = idx / 600, j = idx - n * 600;
    const float* W1i = W1 + (size_t)i * QD * 600;
    const float* qn = q + n * QD;
    int k0 = z * 75;
    float a0 = 0.f;
    #pragma unroll 5
    for (int k = k0; k < k0 + 75; ++k)
        a0 += qn[k] * W1i[(size_t)k * 600 + j];
    t1p[((size_t)(z * NT + i) * Nn + n) * 600 + j] = a0;
}

// K1a-fin: t1 = relu(sum_z t1p). grid (75, NT).
__global__ __launch_bounds__(256) void gates1_fin_kernel(
    const float* __restrict__ t1p, float* __restrict__ t1)
{
    int i = blockIdx.y;
    int idx = blockIdx.x * 256 + threadIdx.x;
    size_t o = ((size_t)i * Nn) * 600 + idx;
    float s = t1p[o] + t1p[o + 76800] + t1p[o + 2 * 76800] + t1p[o + 3 * 76800];
    t1[o] = fmaxf(s, 0.f);
}

// ---------------------------------------------------------------------------
// K1b: gates2 partial. K=600, 4 slabs of 150.
__global__ __launch_bounds__(256) void gates2_part_kernel(
    const float* __restrict__ t1,   // (4, 32, 600)
    const float* __restrict__ W2,   // (4, 600, 600)
    float* __restrict__ gp)         // (4, 4, 32, 600)
{
    int i = blockIdx.y, z = blockIdx.z;
    int idx = blockIdx.x * 256 + threadIdx.x;
    int n = idx / 600, j = idx - n * 600;
    const float* W2i = W2 + (size_t)i * 600 * 600;
    const float* tn = t1 + ((size_t)i * Nn + n) * 600;
    int k0 = z * 150;
    float a0 = 0.f, a1 = 0.f;
    #pragma unroll 5
    for (int k = k0; k < k0 + 150; k += 2) {
        a0 += tn[k]     * W2i[(size_t)k * 600 + j];
        a1 += tn[k + 1] * W2i[(size_t)(k + 1) * 600 + j];
    }
    gp[((size_t)(z * NT + i) * Nn + n) * 600 + j] = a0 + a1;
}

// K1b-fin: gate = sigmoid(sum_z gp) * a  -> GT split planes [i][2n+s][d].
__global__ __launch_bounds__(256) void gates2_fin_kernel(
    const float* __restrict__ gp,
    const float* __restrict__ a,    // (4, 600)
    unsigned short* __restrict__ GTh,   // (4, 64, 320)
    unsigned short* __restrict__ GTl)
{
    int i = blockIdx.y;
    int idx = blockIdx.x * 256 + threadIdx.x;
    int n = idx / 600, j = idx - n * 600;
    size_t o = ((size_t)i * Nn + n) * 600 + j;
    float s = gp[o] + gp[o + 76800] + gp[o + 2 * 76800] + gp[o + 3 * 76800];
    float w = (1.f / (1.f + __expf(-s))) * a[(size_t)i * 600 + j];
    int s2 = (j >= DOUT) ? 1 : 0;
    int d = j - s2 * DOUT;
    int c = 2 * n + s2;
    size_t go = ((size_t)i * 64 + c) * 320 + d;
    unsigned short h = f2bf(w);
    GTh[go] = h;
    GTl[go] = f2bf(w - bf2f(h));
}

// ---------------------------------------------------------------------------
// K2: uvec via MFMA. grid (5, NT), block 256 (4 waves).
__global__ __launch_bounds__(256) void uvec_mfma_kernel(
    const float* __restrict__ W,            // (4, 300, 300)
    const unsigned short* __restrict__ GTh, // (4, 64, 320)
    const unsigned short* __restrict__ GTl,
    unsigned short* __restrict__ UTh,       // (32, 16, 320)
    unsigned short* __restrict__ UTl)
{
    int mc = blockIdx.x, i = blockIdx.y;
    int tid = threadIdx.x, wv = tid >> 6, lane = tid & 63;
    int g = lane >> 4, cr = lane & 15;
    int m0 = mc * 64 + wv * 16;
    int arow = m0 + cr;
    const float* wr = W + (size_t)i * DIN * DOUT
                        + (size_t)(arow < DIN ? arow : 0) * DOUT;

    f32x4 acc[4];
    #pragma unroll
    for (int nt = 0; nt < 4; ++nt) acc[nt] = (f32x4){0.f, 0.f, 0.f, 0.f};

    for (int ks = 0; ks < 10; ++ks) {
        int k0 = ks * 32 + 8 * g;
        float x8[8];
        if (ks < 9) {
            f32x4 v0 = *(const f32x4*)(wr + k0);
            f32x4 v1 = *(const f32x4*)(wr + k0 + 4);
            #pragma unroll
            for (int j = 0; j < 4; ++j) { x8[j] = v0[j]; x8[4 + j] = v1[j]; }
        } else {
            #pragma unroll
            for (int j = 0; j < 8; ++j) {
                int d = k0 + j;
                x8[j] = (d < DOUT) ? wr[d] : 0.f;
            }
        }
        bf16x8 ahi, alo;
        #pragma unroll
        for (int j = 0; j < 8; ++j) {
            unsigned short h = f2bf(x8[j]);
            ahi[j] = (short)h;
            alo[j] = (short)f2bf(x8[j] - bf2f(h));
        }
        #pragma unroll
        for (int nt = 0; nt < 4; ++nt) {
            size_t bo = ((size_t)i * 64 + nt * 16 + cr) * 320 + k0;
            bf16x8 bh = *(const bf16x8*)(GTh + bo);
            bf16x8 bl = *(const bf16x8*)(GTl + bo);
            acc[nt] = __builtin_amdgcn_mfma_f32_16x16x32_bf16(ahi, bh, acc[nt], 0, 0, 0);
            acc[nt] = __builtin_amdgcn_mfma_f32_16x16x32_bf16(ahi, bl, acc[nt], 0, 0, 0);
            acc[nt] = __builtin_amdgcn_mfma_f32_16x16x32_bf16(alo, bh, acc[nt], 0, 0, 0);
        }
    }

    int krow = m0 + 4 * g;
    if (krow < DIN) {
        #pragma unroll
        for (int nt = 0; nt < 4; ++nt) {
            int c = nt * 16 + cr;
            int n = c >> 1, s = c & 1;
            size_t base = ((size_t)n * 16 + 2 * i + s) * 320 + krow;
            u16x4 h4, l4;
            #pragma unroll
            for (int q = 0; q < 4; ++q) {
                float v = acc[nt][q];
                unsigned short h = f2bf(v);
                h4[q] = h;
                l4[q] = f2bf(v - bf2f(h));
            }
            *(u16x4*)(UTh + base) = h4;
            *(u16x4*)(UTl + base) = l4;
        }
    }
}

// ---------------------------------------------------------------------------
// K4: MFMA hm GEMM + fused sdot. 64-row fat tile, 512 threads (8 waves),
// grid 256, XCD-aligned decode. Col-tiles 0..18 only. (proven round-21/23
// form: in-register A-build, 3 col-tiles/wave — the local optimum; both
// 1024-thread variants and pre-split X planes regressed.)
__global__ __launch_bounds__(512) void hm_mfma_kernel(
    const float* __restrict__ X,               // (16384, 300)
    const float* __restrict__ mask,            // (16384)
    const unsigned short* __restrict__ W3T_hi, // (320, 320)
    const unsigned short* __restrict__ W3T_lo,
    const unsigned short* __restrict__ UTh,    // (32, 16, 320)
    const unsigned short* __restrict__ UTl,
    unsigned short* __restrict__ hmT_hi,       // (32, CPAD, 512)
    unsigned short* __restrict__ hmT_lo,
    float* __restrict__ ssrc,                  // (4, 32, 512)
    float* __restrict__ sdst)
{
    int tid = threadIdx.x, wv = tid >> 6, lane = tid & 63;
    int g = lane >> 4, cr = lane & 15;
    int f  = blockIdx.x;                      // 0..255
    int n  = (f & 7) * 4 + ((f >> 3) & 3);    // XCD-local n (matches attn64)
    int j0 = (f >> 5) * 64;                   // 0..448
    size_t row0 = (size_t)n * Ee + j0;

    __shared__ float maskL[64];
    if (tid < 64) maskL[tid] = mask[row0 + tid];
    __syncthreads();

    f32x4 acc[3][4];
    f32x4 sacc[4];
    #pragma unroll
    for (int t = 0; t < 3; ++t)
        #pragma unroll
        for (int m = 0; m < 4; ++m) acc[t][m] = (f32x4){0.f, 0.f, 0.f, 0.f};
    #pragma unroll
    for (int m = 0; m < 4; ++m) sacc[m] = (f32x4){0.f, 0.f, 0.f, 0.f};

    const float* xr0 = X + (row0 +      cr) * DIN;
    const float* xr1 = X + (row0 + 16 + cr) * DIN;
    const float* xr2 = X + (row0 + 32 + cr) * DIN;
    const float* xr3 = X + (row0 + 48 + cr) * DIN;
    const float* xrs[4] = {xr0, xr1, xr2, xr3};

    for (int ks = 0; ks < 10; ++ks) {
        int k0 = ks * 32 + 8 * g;     // per-lane k base
        bf16x8 ahi[4], alo[4];
        #pragma unroll
        for (int m = 0; m < 4; ++m) {
            const float* xr = xrs[m];
            float x8[8];
            if (ks < 9) {
                f32x4 v0 = *(const f32x4*)(xr + k0);
                f32x4 v1 = *(const f32x4*)(xr + k0 + 4);
                #pragma unroll
                for (int j = 0; j < 4; ++j) { x8[j] = v0[j]; x8[4 + j] = v1[j]; }
            } else {
                #pragma unroll
                for (int j = 0; j < 8; ++j) {
                    int k = k0 + j;
                    x8[j] = (k < DIN) ? xr[k] : 0.f;
                }
            }
            #pragma unroll
            for (int j = 0; j < 8; ++j) {
                unsigned short h = f2bf(x8[j]);
                ahi[m][j] = (short)h;
                alo[m][j] = (short)f2bf(x8[j] - bf2f(h));
            }
        }
        #pragma unroll
        for (int t = 0; t < 3; ++t) {
            int ct = wv + 8 * t;
            if (ct < 19) {
                int c = ct * 16 + cr;
                bf16x8 bh = *(const bf16x8*)(W3T_hi + (size_t)c * 320 + k0);
                bf16x8 bl = *(const bf16x8*)(W3T_lo + (size_t)c * 320 + k0);
                #pragma unroll
                for (int m = 0; m < 4; ++m) {
                    acc[t][m] = __builtin_amdgcn_mfma_f32_16x16x32_bf16(ahi[m], bh, acc[t][m], 0, 0, 0);
                    acc[t][m] = __builtin_amdgcn_mfma_f32_16x16x32_bf16(ahi[m], bl, acc[t][m], 0, 0, 0);
                    acc[t][m] = __builtin_amdgcn_mfma_f32_16x16x32_bf16(alo[m], bh, acc[t][m], 0, 0, 0);
                }
            }
        }
        if (wv == 0) {
            bf16x8 uh = *(const bf16x8*)(UTh + ((size_t)n * 16 + cr) * 320 + k0);
            bf16x8 ul = *(const bf16x8*)(UTl + ((size_t)n * 16 + cr) * 320 + k0);
            #pragma unroll
            for (int m = 0; m < 4; ++m) {
                sacc[m] = __builtin_amdgcn_mfma_f32_16x16x32_bf16(ahi[m], uh, sacc[m], 0, 0, 0);
                sacc[m] = __builtin_amdgcn_mfma_f32_16x16x32_bf16(ahi[m], ul, sacc[m], 0, 0, 0);
                sacc[m] = __builtin_amdgcn_mfma_f32_16x16x32_bf16(alo[m], uh, sacc[m], 0, 0, 0);
            }
        }
    }

    // hm epilogue: mask, split, transposed store (q contiguous in j -> 8B)
    #pragma unroll
    for (int t = 0; t < 3; ++t) {
        int ct = wv + 8 * t;
        if (ct < 19) {
            int c = ct * 16 + cr;
            #pragma unroll
            for (int m = 0; m < 4; ++m) {
                u16x4 h4, l4;
                #pragma unroll
                for (int qq = 0; qq < 4; ++qq) {
                    float v = acc[t][m][qq] * maskL[m * 16 + 4 * g + qq];
                    unsigned short h = f2bf(v);
                    h4[qq] = h;
                    l4[qq] = f2bf(v - bf2f(h));
                }
                size_t off = ((size_t)(n * CPAD + c)) * Ee + j0 + m * 16 + 4 * g;
                *(u16x4*)(hmT_hi + off) = h4;
                *(u16x4*)(hmT_lo + off) = l4;
            }
        }
    }

    // sdot epilogue: D[row=m*16+4g+q][c=cr], c=2i -> ssrc, c=2i+1 -> sdst
    if (wv == 0 && cr < 8) {
        int i = cr >> 1;
        float* dst = (cr & 1) ? sdst : ssrc;
        #pragma unroll
        for (int m = 0; m < 4; ++m)
            #pragma unroll
            for (int qq = 0; qq < 4; ++qq)
                dst[((size_t)i * Nn + n) * Ee + j0 + m * 16 + 4 * g + qq] = sacc[m][qq];
    }
}

// ---------------------------------------------------------------------------
// K5: FUSED attn, 64-row fat tile, 1024 threads (round-21 form, KEPT).
__global__ __launch_bounds__(1024, 1) void attn64_kernel(
    const int*   __restrict__ adj,      // (N, E, E)
    const float* __restrict__ ssrc,     // (4, N, E)
    const float* __restrict__ sdst,     // (4, N, E)
    const unsigned short* __restrict__ hmT_hi,  // (32, CPAD, 512)
    const unsigned short* __restrict__ hmT_lo,
    float* __restrict__ out)            // (N, E, 300)
{
    int f  = blockIdx.x;                     // 0..255
    int n  = (f & 7) * 4 + ((f >> 3) & 3);   // XCD-local n
    int rt = f >> 5;                         // 0..7
    int tid = threadIdx.x;
    int row0 = rt * ROWS;

    __shared__ unsigned uni[Ee * USTR];   // 33280 dwords = 133.1 KB (union)
    __shared__ float sdl[NT * Ee];        // 8 KB, XOR-swizzled
    __shared__ float ssl[NT * 65];        // padded
    float* S = (float*)uni;               // phase A view: S[r*SSTR + j]

    for (int idx = tid; idx < NT * Ee; idx += 1024) {
        int i = idx >> 9, j = idx & (Ee - 1);
        sdl[i * Ee + swzj(j)] = sdst[((size_t)i * Nn + n) * Ee + j];
    }
    if (tid < NT * ROWS) {
        int i = tid >> 6, r = tid & 63;
        ssl[i * 65 + r] = ssrc[((size_t)i * Nn + n) * Ee + row0 + r];
    }
    __syncthreads();

    // scores: int4 adj, swizzled sdl gather, aligned f4 writes
    const int* adjb = adj + ((size_t)n * Ee + row0) * Ee;
    for (int idx4 = tid; idx4 < (ROWS * Ee) / 4; idx4 += 1024) {
        int r  = idx4 >> 7;
        int jb = (idx4 & 127) << 2;
        int xw = (jb >> 5) & 3;
        int4 t4 = *(const int4*)(adjb + (idx4 << 2));
        int tv[4] = {t4.x, t4.y, t4.z, t4.w};
        f32x4 v4;
        #pragma unroll
        for (int u = 0; u < 4; ++u) {
            int t = tv[u];
            float v;
            if (t > 0) {
                float x = ssl[(t - 1) * 65 + r] + sdl[(t - 1) * Ee + jb + (u ^ xw)];
                v = (x >= 0.f) ? x : SLOPE * x;
            } else {
                v = -1e30f;
            }
            v4[u] = v;   // column-ordered placement
        }
        *(f32x4*)(S + r * SSTR + jb) = v4;
    }
    __syncthreads();

    // softmax: wave wv owns rows wv*4..+3, values in registers
    int wv = tid >> 6, lane = tid & 63;
    float vals[4][8];
    float inv[4];
    #pragma unroll
    for (int rr = 0; rr < 4; ++rr) {
        int r = wv * 4 + rr;
        float m = -3.0e38f;
        #pragma unroll
        for (int k = 0; k < 8; ++k) {
            vals[rr][k] = S[r * SSTR + lane + 64 * k];
            m = fmaxf(m, vals[rr][k]);
        }
        #pragma unroll
        for (int off = 32; off; off >>= 1) m = fmaxf(m, __shfl_xor(m, off));
        float s = 0.f;
        #pragma unroll
        for (int k = 0; k < 8; ++k) {
            vals[rr][k] = __expf(vals[rr][k] - m);
            s += vals[rr][k];
        }
        #pragma unroll
        for (int off = 32; off; off >>= 1) s += __shfl_xor(s, off);
        inv[rr] = 1.f / s;
    }
    __syncthreads();   // all S reads done; safe to overwrite union as coefU

    // packed write coefU[j][r] (stride 65): bank = lane + const -> free
    #pragma unroll
    for (int rr = 0; rr < 4; ++rr) {
        int r = wv * 4 + rr;
        #pragma unroll
        for (int k = 0; k < 8; ++k) {
            float v = vals[rr][k] * inv[rr];
            unsigned short hi = f2bf(v);
            unsigned short lo = f2bf(v - bf2f(hi));
            uni[(lane + 64 * k) * USTR + r] = ((unsigned)hi << 16) | (unsigned)lo;
        }
    }
    __syncthreads();

    // PV: wave wv owns col-tiles {wv, wv+16} ∩ [0,19); 4 m-frags each
    int g = lane >> 4, cr = lane & 15;
    f32x4 acc[2][4];
    #pragma unroll
    for (int t = 0; t < 2; ++t)
        #pragma unroll
        for (int m = 0; m < 4; ++m) acc[t][m] = (f32x4){0.f, 0.f, 0.f, 0.f};

#define LOADB(BH, BL, KS) do {                                              \
    int kk_ = (KS) * 32 + 8 * g;                                            \
    _Pragma("unroll")                                                       \
    for (int t_ = 0; t_ < 2; ++t_) {                                        \
        int ct_ = wv + 16 * t_;                                             \
        if (ct_ < 19) {                                                     \
            size_t off_ = ((size_t)(n * CPAD + ct_ * 16 + cr)) * Ee + kk_;  \
            BH[t_] = *(const bf16x8*)(hmT_hi + off_);                       \
            BL[t_] = *(const bf16x8*)(hmT_lo + off_);                       \
        }                                                                   \
    }                                                                       \
} while (0)

#define PVSTEP(KS, BH, BL) do {                                             \
    int kk_ = (KS) * 32;                                                    \
    bf16x8 ahi_[4], alo_[4];                                                \
    _Pragma("unroll")                                                       \
    for (int m_ = 0; m_ < 4; ++m_) {                                        \
        _Pragma("unroll")                                                   \
        for (int j_ = 0; j_ < 8; ++j_) {                                    \
            unsigned v_ = uni[(kk_ + 8 * g + j_) * USTR + m_ * 16 + cr];    \
            ahi_[m_][j_] = (short)(v_ >> 16);                               \
            alo_[m_][j_] = (short)(v_ & 0xffffu);                           \
        }                                                                   \
    }                                                                       \
    __builtin_amdgcn_s_setprio(1);                                          \
    _Pragma("unroll")                                                       \
    for (int t_ = 0; t_ < 2; ++t_) {                                        \
        if (wv + 16 * t_ < 19) {                                            \
            _Pragma("unroll")                                               \
            for (int m_ = 0; m_ < 4; ++m_) {                                \
                acc[t_][m_] = __builtin_amdgcn_mfma_f32_16x16x32_bf16(ahi_[m_], BH[t_], acc[t_][m_], 0, 0, 0); \
                acc[t_][m_] = __builtin_amdgcn_mfma_f32_16x16x32_bf16(ahi_[m_], BL[t_], acc[t_][m_], 0, 0, 0); \
                acc[t_][m_] = __builtin_amdgcn_mfma_f32_16x16x32_bf16(alo_[m_], BH[t_], acc[t_][m_], 0, 0, 0); \
            }                                                               \
        }                                                                   \
    }                                                                       \
    __builtin_amdgcn_s_setprio(0);                                          \
} while (0)

    bf16x8 bhA[2], blA[2], bhB[2], blB[2];
    LOADB(bhA, blA, 0);
    #pragma unroll
    for (int ks = 0; ks < 16; ks += 2) {
        LOADB(bhB, blB, ks + 1);
        PVSTEP(ks, bhA, blA);
        if (ks + 2 < 16) LOADB(bhA, blA, ks + 2);
        PVSTEP(ks + 1, bhB, blB);
    }
#undef LOADB
#undef PVSTEP

    #pragma unroll
    for (int t = 0; t < 2; ++t) {
        int ct = wv + 16 * t;
        if (ct < 19) {
            int c = ct * 16 + cr;
            if (c < DOUT) {
                #pragma unroll
                for (int m = 0; m < 4; ++m) {
                    #pragma unroll
                    for (int q = 0; q < 4; ++q) {
                        int erow = row0 + m * 16 + 4 * g + q;
                        out[((size_t)n * Ee + erow) * DOUT + c] = acc[t][m][q];
                    }
                }
            }
        }
    }
}

// ---------------------------------------------------------------------------
extern "C" void kernel_launch(void* const* d_in, const int* in_sizes, int n_in,
                              void* d_out, int out_size, void* d_ws, size_t ws_size,
                              hipStream_t stream) {
    const float* input_state = (const float*)d_in[0];
    const int*   adj         = (const int*)  d_in[1];
    const float* node_mask   = (const float*)d_in[2];
    const float* query_vec   = (const float*)d_in[3];
    const float* W_type      = (const float*)d_in[4];
    const float* a_type      = (const float*)d_in[5];
    const float* qattn_W1    = (const float*)d_in[6];
    const float* qattn_W2    = (const float*)d_in[7];
    float* out = (float*)d_out;

    // workspace layout (~25 MB)
    float* ws   = (float*)d_ws;
    float* t1   = ws;                 // 76800 f
    float* ssrc = t1   + 76800;       // 65536 f
    float* sdst = ssrc + 65536;       // 65536 f
    unsigned short* W3T_hi = (unsigned short*)(sdst + 65536);   // 102400 u16
    unsigned short* W3T_lo = W3T_hi + 320 * 320;                // 102400 u16
    unsigned short* GTh    = W3T_lo + 320 * 320;                // 81920 u16
    unsigned short* GTl    = GTh + 4 * 64 * 320;                // 81920 u16
    unsigned short* UTh    = GTl + 4 * 64 * 320;                // 163840 u16
    unsigned short* UTl    = UTh + 32 * 16 * 320;               // 163840 u16
    unsigned short* hmT_hi = UTl + 32 * 16 * 320;               // 5242880 u16
    unsigned short* hmT_lo = hmT_hi + (size_t)Nn * CPAD * Ee;   // 5242880 u16
    float* t1p = (float*)(hmT_lo + (size_t)Nn * CPAD * Ee);     // 307200 f
    float* gp  = t1p + 307200;                                  // 307200 f

    hipLaunchKernelGGL(prep_kernel, dim3(640), dim3(256), 0, stream,
                       W_type + 3 * DIN * DOUT, W3T_hi, W3T_lo, UTh, UTl, GTh, GTl);
    hipLaunchKernelGGL(gates1_part_kernel, dim3(75, NT, 4), dim3(256), 0, stream,
                       query_vec, qattn_W1, t1p);
    hipLaunchKernelGGL(gates1_fin_kernel, dim3(75, NT), dim3(256), 0, stream,
                       t1p, t1);
    hipLaunchKernelGGL(gates2_part_kernel, dim3(75, NT, 4), dim3(256), 0, stream,
                       t1, qattn_W2, gp);
    hipLaunchKernelGGL(gates2_fin_kernel, dim3(75, NT), dim3(256), 0, stream,
                       gp, a_type, GTh, GTl);
    hipLaunchKernelGGL(uvec_mfma_kernel, dim3(5, NT), dim3(256), 0, stream,
                       W_type, GTh, GTl, UTh, UTl);
    hipLaunchKernelGGL(hm_mfma_kernel, dim3((Nn * Ee) / 64), dim3(512), 0, stream,
                       input_state, node_mask, W3T_hi, W3T_lo, UTh, UTl,
                       hmT_hi, hmT_lo, ssrc, sdst);
    hipLaunchKernelGGL(attn64_kernel, dim3(256), dim3(1024), 0, stream,
                       adj, ssrc, sdst, hmT_hi, hmT_lo, out);
}